// Round 15
// baseline (379.810 us; speedup 1.0000x reference)
//
#include <hip/hip_runtime.h>
#include <hip/hip_bf16.h>

#define HID 256
#define LN_EPS 1e-5f
#define NEG_SLOPE 0.2f
#define BM 128
#define BN 256
#define BK 32

typedef __attribute__((ext_vector_type(8))) short short8;
typedef __attribute__((ext_vector_type(4))) float f32x4;

__device__ __forceinline__ float gelu_exact(float x){
  return 0.5f*x*(1.0f + erff(x*0.7071067811865476f));
}
__device__ __forceinline__ float lrelu(float x){ return x>0.f ? x : NEG_SLOPE*x; }
__device__ __forceinline__ float wave_sum64(float v){
  #pragma unroll
  for (int o=32;o>0;o>>=1) v += __shfl_xor(v,o,64);
  return v;
}
__device__ __forceinline__ void wave_sum64_x4(float& a, float& b, float& c, float& d){
  #pragma unroll
  for (int o=32;o>0;o>>=1){
    a += __shfl_xor(a,o,64);
    b += __shfl_xor(b,o,64);
    c += __shfl_xor(c,o,64);
    d += __shfl_xor(d,o,64);
  }
}
__device__ __forceinline__ unsigned short f2bf(float x){
  unsigned u = __float_as_uint(x);
  u = (u + 0x7FFFu + ((u>>16)&1u)) >> 16;
  return (unsigned short)u;
}
__device__ __forceinline__ float bf2f(unsigned short u){
  return __uint_as_float(((unsigned)u)<<16);
}
__device__ __forceinline__ void gload_lds16(const void* g, void* l){
  __builtin_amdgcn_global_load_lds((const __attribute__((address_space(1))) unsigned int*)g,
                                   (__attribute__((address_space(3))) unsigned int*)l, 16, 0, 0);
}

// ---------------- f32 -> bf16 streaming convert ----------------
__global__ __launch_bounds__(256) void cvt_bf16_k(const float* __restrict__ in,
                                                  unsigned short* __restrict__ out, long n){
  long i = ((long)blockIdx.x*blockDim.x + threadIdx.x)*8;
  const long stride = (long)gridDim.x*blockDim.x*8;
  for (; i < n; i += stride){
    float4 a = *(const float4*)(in+i);
    float4 b = *(const float4*)(in+i+4);
    short8 c;
    c[0]=(short)f2bf(a.x); c[1]=(short)f2bf(a.y); c[2]=(short)f2bf(a.z); c[3]=(short)f2bf(a.w);
    c[4]=(short)f2bf(b.x); c[5]=(short)f2bf(b.y); c[6]=(short)f2bf(b.z); c[7]=(short)f2bf(b.w);
    *(short8*)(out+i) = c;
  }
}

// ---------------- edge preprocessing: counting sort by dst ----------------
__global__ void edge_hist_k(const int* __restrict__ edges, int* __restrict__ count, int nE, int nN){
  int j = blockIdx.x*blockDim.x + threadIdx.x;
  if (j >= nE+nN) return;
  int dst = (j<nE) ? edges[nE+j] : (j-nE);
  atomicAdd(&count[dst], 1);
}

// 3-phase parallel scan
__global__ __launch_bounds__(256) void scan1_k(const int* __restrict__ count, int* __restrict__ off,
                                               int* __restrict__ bsum, int n, int chunk){
  __shared__ int sh[256];
  const int b = blockIdx.x, t = threadIdx.x;
  const int idx = b*chunk + t;
  int v = (t < chunk && idx < n) ? count[idx] : 0;
  sh[t] = v; __syncthreads();
  int val = v;
  for (int d=1; d<256; d<<=1){
    int tv = (t>=d) ? sh[t-d] : 0;
    __syncthreads();
    val += tv; sh[t] = val;
    __syncthreads();
  }
  if (t < chunk && idx < n) off[idx] = val;
  if (t == 255) bsum[b] = val;
}
__global__ __launch_bounds__(256) void scan2_k(const int* __restrict__ bsum, int* __restrict__ boff,
                                               int* __restrict__ off, int n, int nb){
  __shared__ int sh[256];
  const int t = threadIdx.x;
  int v = (t<nb) ? bsum[t] : 0;
  sh[t] = v; __syncthreads();
  int val = v;
  for (int d=1; d<256; d<<=1){
    int tv = (t>=d) ? sh[t-d] : 0;
    __syncthreads();
    val += tv; sh[t] = val;
    __syncthreads();
  }
  boff[t] = val - v;
  if (t == 255) off[n] = val;
}
__global__ __launch_bounds__(256) void scan3_k(const int* __restrict__ count, const int* __restrict__ boff,
                                               int* __restrict__ off, int n, int chunk){
  const int idx = blockIdx.x*chunk + threadIdx.x;
  if (threadIdx.x < chunk && idx < n)
    off[idx] = off[idx] - count[idx] + boff[blockIdx.x];
}

// scatter + mark srcs of edges with dst < 4096 (for layer-3 row filtering)
__global__ void edge_scatter_k(const int* __restrict__ edges, const int* __restrict__ off,
                               int* __restrict__ cursor, int* __restrict__ ssrc,
                               int* __restrict__ mark, int nE, int nN){
  int j = blockIdx.x*blockDim.x + threadIdx.x;
  if (j >= nE+nN) return;
  int src, dst;
  if (j<nE){ src=edges[j]; dst=edges[nE+j]; } else { src=j-nE; dst=src; }
  int pos = off[dst] + atomicAdd(&cursor[dst],1);
  ssrc[pos]=src;
  if (dst < 4096) mark[src] = 1;      // benign race: all write 1
}

// unsorted compaction of marked rows
__global__ void compact_k(const int* __restrict__ mark, int* __restrict__ rowmap,
                          int* __restrict__ cnt, int n){
  int i = blockIdx.x*blockDim.x + threadIdx.x;
  if (i < n && mark[i]) rowmap[atomicAdd(cnt,1)] = i;
}

// ---------------- merged transpose: 5 weight matrices in one dispatch ----------------
__global__ __launch_bounds__(256) void transpose5_k(
    const float* __restrict__ sWc, unsigned short* __restrict__ dWc,
    const float* __restrict__ s2l, const float* __restrict__ s2r, unsigned short* __restrict__ dW2,
    const float* __restrict__ s3l, const float* __restrict__ s3r, unsigned short* __restrict__ dW3)
{
  __shared__ float t[32][33];
  int b = blockIdx.x;
  const float* in; unsigned short* out; int K, N, kb, nb;
  if (b < 192){ in=sWc; out=dWc; K=768; N=256; kb=(b%24)*32; nb=(b/24)*32; }
  else {
    int j=(b-192)>>6, r=(b-192)&63;
    K=256; N=256; kb=(r&7)*32; nb=(r>>3)*32;
    in  = (j==0)?s2l:(j==1)?s2r:(j==2)?s3l:s3r;
    out = (j==0)?dW2:(j==1)?(dW2+256*256):(j==2)?dW3:(dW3+256*256);
  }
  const int tx = threadIdx.x & 31, ty = threadIdx.x >> 5;
  #pragma unroll
  for (int r=ty; r<32; r+=8){
    if (kb+r < K && nb+tx < N) t[r][tx] = in[(long)(kb+r)*N + nb+tx];
  }
  __syncthreads();
  #pragma unroll
  for (int r=ty; r<32; r+=8){
    if (nb+r < N && kb+tx < K) out[(long)(nb+r)*K + kb+tx] = f2bf(t[tx][r]);
  }
}

// ---------------- word branch: VALU GEMM + bias + LN + GELU ----------------
__global__ __launch_bounds__(256) void word_gemm_ln_gelu_k(
    const float* __restrict__ X, const float* __restrict__ W,
    const float* __restrict__ bias, const float* __restrict__ gamma,
    const float* __restrict__ beta, float* __restrict__ out, int K)
{
  const int tid = threadIdx.x;
  const long row0 = (long)blockIdx.x * 4;
  float acc[4] = {0.f,0.f,0.f,0.f};
  const float* Xb = X + row0*K;
  for (int k=0;k<K;k+=4){
    float w0=W[(long)(k+0)*HID+tid];
    float w1=W[(long)(k+1)*HID+tid];
    float w2=W[(long)(k+2)*HID+tid];
    float w3=W[(long)(k+3)*HID+tid];
    #pragma unroll
    for (int r=0;r<4;r++){
      const float* xp = Xb + (long)r*K + k;
      acc[r] = fmaf(xp[0],w0, fmaf(xp[1],w1, fmaf(xp[2],w2, fmaf(xp[3],w3, acc[r]))));
    }
  }
  __shared__ float red[8];
  const float bv=bias[tid], gv=gamma[tid], btv=beta[tid];
  const int wid=tid>>6, lane=tid&63;
  #pragma unroll
  for (int r=0;r<4;r++){
    float v = acc[r]+bv;
    float p1 = wave_sum64(v), p2 = wave_sum64(v*v);
    __syncthreads();
    if (lane==0){ red[wid]=p1; red[4+wid]=p2; }
    __syncthreads();
    float S1=red[0]+red[1]+red[2]+red[3];
    float S2=red[4]+red[5]+red[6]+red[7];
    float mu = S1*(1.f/HID);
    float var = S2*(1.f/HID) - mu*mu;
    float rs = rsqrtf(var + LN_EPS);
    out[(row0+r)*HID + tid] = gelu_exact((v-mu)*rs*gv + btv);
  }
}

// ---------------- FUSED: G = gelu(LN(X@Wc+bc)); xl|xr = G@[W2l|W2r]+[bl|br] ----------------
// R9's measured-best form: phase-2 W2 staged via gload_lds 3-slot pipeline.
__global__ __launch_bounds__(512) void fused_gloss_proj_k(
    const unsigned short* __restrict__ X, const unsigned short* __restrict__ Wt,
    const float* __restrict__ bc, const float* __restrict__ gc1, const float* __restrict__ bc1,
    const unsigned short* __restrict__ W2,
    const float* __restrict__ bl, const float* __restrict__ br,
    unsigned short* __restrict__ xlr, int M)
{
  constexpr int SLOT1 = BM*BK*2 + BN*BK*2;   // 24KB
  constexpr int B2OFF = 3*SLOT1;             // 72KB (G overlays [0,64KB) after phase1)
  constexpr int SLOT2 = 256*BK*2;            // 16KB
  __shared__ __align__(16) char lds[B2OFF + 3*SLOT2];   // 120KB
  __shared__ float red_s[BM][4], red_q[BM][4];

  const int tid = threadIdx.x;
  const int wid = tid>>6, lane = tid&63;
  const int wr = wid>>2, wc = wid&3;
  const int lhi = lane>>4, llo = lane&15;
  const long r0 = (long)blockIdx.x * BM;

  // ================= phase 1: G tile =================
  {
    f32x4 acc[4][4] = {};
    long ar = r0 + (tid>>2); if (ar > (long)M-1) ar = (long)M-1;
    const unsigned short* gA  = X + ar*768 + (tid&3)*8;
    const unsigned short* gB0 = Wt + (long)(tid>>2)*768 + (tid&3)*8;
    const unsigned short* gB1 = Wt + (long)(128 + (tid>>2))*768 + (tid&3)*8;

    auto stage1 = [&](int s){
      char* b = lds + s*SLOT1;
      gload_lds16(gA,  b + tid*16);         gA  += BK;
      gload_lds16(gB0, b + 8192 + tid*16);  gB0 += BK;
      gload_lds16(gB1, b + 16384 + tid*16); gB1 += BK;
    };
    int offA[4], offB[4];
    #pragma unroll
    for (int m=0;m<4;m++) offA[m] = (wr*64 + m*16 + llo)*64 + lhi*16;
    #pragma unroll
    for (int n=0;n<4;n++) offB[n] = 8192 + (wc*64 + n*16 + llo)*64 + lhi*16;

    stage1(0); stage1(1);
    int cs = 0, ps = 2;
    for (int kt=0; kt<24; ++kt){
      if (kt+1 < 24) asm volatile("s_waitcnt vmcnt(3)" ::: "memory");
      else           asm volatile("s_waitcnt vmcnt(0)" ::: "memory");
      __builtin_amdgcn_s_barrier();
      if (kt+2 < 24) stage1(ps);
      const char* base = lds + cs*SLOT1;
      short8 a[4], b[4];
      #pragma unroll
      for (int m=0;m<4;m++) a[m] = *(const short8*)(base + offA[m]);
      #pragma unroll
      for (int n=0;n<4;n++) b[n] = *(const short8*)(base + offB[n]);
      #pragma unroll
      for (int m=0;m<4;m++)
        #pragma unroll
        for (int n=0;n<4;n++)
          acc[m][n] = __builtin_amdgcn_mfma_f32_16x16x32_bf16(a[m], b[n], acc[m][n], 0,0,0);
      cs = (cs==2)?0:cs+1;
      ps = (ps==2)?0:ps+1;
    }

    // LN + GELU epilogue -> G in LDS (chunk-XOR swizzled), overlaying staging slots
    const int colb = wc*64 + llo;
    float bv[4], gv[4], btv[4];
    #pragma unroll
    for (int n=0;n<4;n++){ bv[n]=bc[colb+n*16]; gv[n]=gc1[colb+n*16]; btv[n]=bc1[colb+n*16]; }
    __syncthreads();                      // all slot reads complete before G overwrite
    #pragma unroll
    for (int m=0;m<4;m++){
      #pragma unroll
      for (int reg=0;reg<4;reg++){
        float s=0.f, q=0.f;
        #pragma unroll
        for (int n=0;n<4;n++){ float v=acc[m][n][reg]+bv[n]; s+=v; q+=v*v; }
        #pragma unroll
        for (int msk=1;msk<16;msk<<=1){ s += __shfl_xor(s,msk,64); q += __shfl_xor(q,msk,64); }
        if (llo==0){ int rl = wr*64+m*16+lhi*4+reg; red_s[rl][wc]=s; red_q[rl][wc]=q; }
      }
    }
    __syncthreads();
    #pragma unroll
    for (int m=0;m<4;m++){
      #pragma unroll
      for (int reg=0;reg<4;reg++){
        int rl = wr*64+m*16+lhi*4+reg;
        float S1 = red_s[rl][0]+red_s[rl][1]+red_s[rl][2]+red_s[rl][3];
        float S2 = red_q[rl][0]+red_q[rl][1]+red_q[rl][2]+red_q[rl][3];
        float mu = S1*(1.f/256.f);
        float var = S2*(1.f/256.f) - mu*mu;
        float rs = rsqrtf(var + LN_EPS);
        #pragma unroll
        for (int n=0;n<4;n++){
          int col = colb + n*16;
          float y = gelu_exact((acc[m][n][reg]+bv[n]-mu)*rs*gv[n] + btv[n]);
          int byte = rl*512 + (((col>>3) ^ (rl&7))<<4) + (col&7)*2;
          *(unsigned short*)(lds + byte) = f2bf(y);
        }
      }
    }
  }
  __syncthreads();                        // G complete & visible

  // ================= phase 2: xl | xr (W2 staged via gload_lds, 3 slots) =================
  for (int pass=0; pass<2; ++pass){
    const unsigned short* Wp = W2 + (size_t)pass*256*256;
    const unsigned short* gW0 = Wp + (long)(tid>>2)*256 + (tid&3)*8;          // rows 0..127
    const unsigned short* gW1 = Wp + (long)(128 + (tid>>2))*256 + (tid&3)*8;  // rows 128..255
    auto stage2 = [&](int s){
      char* b = lds + B2OFF + s*SLOT2;
      gload_lds16(gW0, b + tid*16);        gW0 += BK;
      gload_lds16(gW1, b + 8192 + tid*16); gW1 += BK;
    };
    f32x4 acc2[4][4] = {};
    __syncthreads();                      // prev pass reads done before slot reuse
    stage2(0); stage2(1);
    int cs = 0, ps = 2;
    for (int kt=0; kt<8; ++kt){
      if (kt+1 < 8) asm volatile("s_waitcnt vmcnt(2)" ::: "memory");
      else          asm volatile("s_waitcnt vmcnt(0)" ::: "memory");
      __builtin_amdgcn_s_barrier();
      if (kt+2 < 8) stage2(ps);
      const char* b2base = lds + B2OFF + cs*SLOT2;
      short8 a2[4], b2[4];
      #pragma unroll
      for (int m=0;m<4;m++){
        int row = wr*64 + m*16 + llo;
        int chunk = (kt*4 + lhi) ^ (row&7);
        a2[m] = *(const short8*)(lds + row*512 + chunk*16);
      }
      #pragma unroll
      for (int n=0;n<4;n++) b2[n] = *(const short8*)(b2base + (wc*64 + n*16 + llo)*64 + lhi*16);
      #pragma unroll
      for (int m=0;m<4;m++)
        #pragma unroll
        for (int n=0;n<4;n++)
          acc2[m][n] = __builtin_amdgcn_mfma_f32_16x16x32_bf16(a2[m], b2[n], acc2[m][n], 0,0,0);
      cs = (cs==2)?0:cs+1;
      ps = (ps==2)?0:ps+1;
    }
    const int colb = wc*64 + llo;
    const float* bias = pass ? br : bl;
    float bv[4];
    #pragma unroll
    for (int n=0;n<4;n++) bv[n] = bias[colb + n*16];
    #pragma unroll
    for (int m=0;m<4;m++){
      #pragma unroll
      for (int reg=0;reg<4;reg++){
        long row = r0 + wr*64 + m*16 + lhi*4 + reg;
        if (row < M){
          #pragma unroll
          for (int n=0;n<4;n++)
            xlr[row*512 + pass*256 + colb + n*16] = f2bf(acc2[m][n][reg] + bv[n]);
        }
      }
    }
  }
}

// ---------------- dual GEMM (BN=256, R13 form) + job-A row filtering ----------------
// jobA: xl3[rowmap[r]] = Gb[rowmap[r]] @ W3l^T + bl for r < *cntA (blocks past cnt exit)
// jobB: xr3 = Gb @ W3r^T + br over MB rows
__global__ __launch_bounds__(512) void mfma_gemm_dual_k(
    const unsigned short* __restrict__ X,
    const unsigned short* __restrict__ WtA, const float* __restrict__ biasA,
    unsigned short* __restrict__ outA, const int* __restrict__ rowmapA,
    const int* __restrict__ cntA, int nblkA,
    const unsigned short* __restrict__ WtB, const float* __restrict__ biasB,
    unsigned short* __restrict__ outB, int MB, int K)
{
  constexpr int ABYTES = BM*BK*2;
  constexpr int SLOT = ABYTES + BN*BK*2;
  __shared__ __align__(16) char lds[3*SLOT];

  const bool jobA = (int)blockIdx.x < nblkA;
  const int bx = jobA ? blockIdx.x : (blockIdx.x - nblkA);
  const long r0 = (long)bx * BM;
  int Mcap;
  if (jobA){ Mcap = cntA[0]; if (r0 >= Mcap) return; }
  else      Mcap = MB;

  const unsigned short* Wt = jobA ? WtA : WtB;
  const float* bias = jobA ? biasA : biasB;
  unsigned short* out = jobA ? outA : outB;

  const int tid = threadIdx.x;
  const int wid = tid>>6, lane = tid&63;
  const int wr = wid>>2, wc = wid&3;
  const int lhi = lane>>4, llo = lane&15;

  f32x4 acc[4][4] = {};

  long rr = r0 + (tid>>2); if (rr > (long)Mcap-1) rr = Mcap-1;
  long ar = jobA ? (long)rowmapA[rr] : rr;
  const unsigned short* gA = X + ar*(long)K + (tid&3)*8;
  const unsigned short* gB0 = Wt + (long)(tid>>2)*K + (tid&3)*8;
  const unsigned short* gB1 = Wt + (long)(128 + (tid>>2))*K + (tid&3)*8;

  auto stage = [&](int s){
    char* base = lds + s*SLOT;
    gload_lds16(gA,  base + tid*16);                 gA  += BK;
    gload_lds16(gB0, base + ABYTES + tid*16);        gB0 += BK;
    gload_lds16(gB1, base + ABYTES + 8192 + tid*16); gB1 += BK;
  };

  int offA[4], offB[4];
  #pragma unroll
  for (int m=0;m<4;m++) offA[m] = (wr*64 + m*16 + llo)*64 + lhi*16;
  #pragma unroll
  for (int n=0;n<4;n++) offB[n] = ABYTES + (wc*64 + n*16 + llo)*64 + lhi*16;

  const int ksteps = K/BK;
  stage(0); stage(1);
  int cs = 0, ps = 2;
  for (int kt=0; kt<ksteps; ++kt){
    if (kt+1 < ksteps) asm volatile("s_waitcnt vmcnt(3)" ::: "memory");
    else               asm volatile("s_waitcnt vmcnt(0)" ::: "memory");
    __builtin_amdgcn_s_barrier();
    if (kt+2 < ksteps) stage(ps);
    const char* base = lds + cs*SLOT;
    short8 a[4], b[4];
    #pragma unroll
    for (int m=0;m<4;m++) a[m] = *(const short8*)(base + offA[m]);
    #pragma unroll
    for (int n=0;n<4;n++) b[n] = *(const short8*)(base + offB[n]);
    #pragma unroll
    for (int m=0;m<4;m++)
      #pragma unroll
      for (int n=0;n<4;n++)
        acc[m][n] = __builtin_amdgcn_mfma_f32_16x16x32_bf16(a[m], b[n], acc[m][n], 0,0,0);
    cs = (cs==2)?0:cs+1;
    ps = (ps==2)?0:ps+1;
  }

  const int colb = wc*64 + llo;
  float bv[4];
  #pragma unroll
  for (int n=0;n<4;n++) bv[n] = bias[colb + n*16];

  #pragma unroll
  for (int m=0;m<4;m++){
    #pragma unroll
    for (int reg=0;reg<4;reg++){
      long row = r0 + wr*64 + m*16 + lhi*4 + reg;
      if (row < Mcap){
        long orow = jobA ? (long)rowmapA[row] : row;
        #pragma unroll
        for (int n=0;n<4;n++)
          out[orow*256 + colb + n*16] = f2bf(acc[m][n][reg] + bv[n]);
      }
    }
  }
}

// ---------------- per-dst GATv2 (wave per dst), 4-edge batched, online softmax + LN + GELU ----------------
template<bool BF16OUT>
__global__ __launch_bounds__(256) void gat_edge_k(
    const unsigned short* __restrict__ xl, int ldl,
    const unsigned short* __restrict__ xr, int ldr,
    const int* __restrict__ off, const int* __restrict__ ssrc,
    const float* __restrict__ att, const float* __restrict__ bias,
    const float* __restrict__ gamma, const float* __restrict__ beta,
    void* __restrict__ gout, int ndst)
{
  const int lane = threadIdx.x & 63;
  const int d = blockIdx.x*4 + (threadIdx.x>>6);
  if (d >= ndst) return;
  const float4 att4 = ((const float4*)att)[lane];
  ushort4 ru = ((const ushort4*)(xr + (size_t)d*ldr))[lane];
  const float rx=bf2f(ru.x), ry=bf2f(ru.y), rz=bf2f(ru.z), rw=bf2f(ru.w);
  const int e0=off[d], e1=off[d+1];
  float m=-1e30f, denom=0.f;
  float4 acc={0.f,0.f,0.f,0.f};

  int i = e0;
  for (; i+4 <= e1; i += 4){
    int s0=ssrc[i], s1=ssrc[i+1], s2=ssrc[i+2], s3=ssrc[i+3];
    ushort4 u0=((const ushort4*)(xl+(size_t)s0*ldl))[lane];
    ushort4 u1=((const ushort4*)(xl+(size_t)s1*ldl))[lane];
    ushort4 u2=((const ushort4*)(xl+(size_t)s2*ldl))[lane];
    ushort4 u3=((const ushort4*)(xl+(size_t)s3*ldl))[lane];
    float a0x=bf2f(u0.x),a0y=bf2f(u0.y),a0z=bf2f(u0.z),a0w=bf2f(u0.w);
    float a1x=bf2f(u1.x),a1y=bf2f(u1.y),a1z=bf2f(u1.z),a1w=bf2f(u1.w);
    float a2x=bf2f(u2.x),a2y=bf2f(u2.y),a2z=bf2f(u2.z),a2w=bf2f(u2.w);
    float a3x=bf2f(u3.x),a3y=bf2f(u3.y),a3z=bf2f(u3.z),a3w=bf2f(u3.w);
    float e0v = att4.x*lrelu(a0x+rx)+att4.y*lrelu(a0y+ry)+att4.z*lrelu(a0z+rz)+att4.w*lrelu(a0w+rw);
    float e1v = att4.x*lrelu(a1x+rx)+att4.y*lrelu(a1y+ry)+att4.z*lrelu(a1z+rz)+att4.w*lrelu(a1w+rw);
    float e2v = att4.x*lrelu(a2x+rx)+att4.y*lrelu(a2y+ry)+att4.z*lrelu(a2z+rz)+att4.w*lrelu(a2w+rw);
    float e3v = att4.x*lrelu(a3x+rx)+att4.y*lrelu(a3y+ry)+att4.z*lrelu(a3z+rz)+att4.w*lrelu(a3w+rw);
    wave_sum64_x4(e0v, e1v, e2v, e3v);
    float bm = fmaxf(fmaxf(e0v,e1v), fmaxf(e2v,e3v));
    if (bm > m){
      float sc = expf(m - bm);
      denom *= sc; acc.x*=sc; acc.y*=sc; acc.z*=sc; acc.w*=sc;
      m = bm;
    }
    float x0=expf(e0v-m), x1=expf(e1v-m), x2=expf(e2v-m), x3=expf(e3v-m);
    denom += x0+x1+x2+x3;
    acc.x += x0*a0x + x1*a1x + x2*a2x + x3*a3x;
    acc.y += x0*a0y + x1*a1y + x2*a2y + x3*a3y;
    acc.z += x0*a0z + x1*a1z + x2*a2z + x3*a3z;
    acc.w += x0*a0w + x1*a1w + x2*a2w + x3*a3w;
  }
  for (; i < e1; ++i){
    int src=ssrc[i];
    ushort4 au = ((const ushort4*)(xl + (size_t)src*ldl))[lane];
    float ax=bf2f(au.x), ay=bf2f(au.y), az=bf2f(au.z), aw=bf2f(au.w);
    float e = att4.x*lrelu(ax+rx)+att4.y*lrelu(ay+ry)
            + att4.z*lrelu(az+rz)+att4.w*lrelu(aw+rw);
    e = wave_sum64(e);
    if (e > m){
      float sc = expf(m - e);
      denom *= sc; acc.x*=sc; acc.y*=sc; acc.z*=sc; acc.w*=sc;
      m = e;
    }
    float ee = expf(e - m);
    denom += ee;
    acc.x += ee*ax; acc.y += ee*ay; acc.z += ee*az; acc.w += ee*aw;
  }

  float inv = 1.0f/denom;
  const float4 b4=((const float4*)bias)[lane];
  float4 o;
  o.x=acc.x*inv+b4.x; o.y=acc.y*inv+b4.y; o.z=acc.z*inv+b4.z; o.w=acc.w*inv+b4.w;
  float S1 = wave_sum64(o.x+o.y+o.z+o.w);
  float S2 = wave_sum64(o.x*o.x+o.y*o.y+o.z*o.z+o.w*o.w);
  float mu=S1*(1.f/256.f);
  float var=S2*(1.f/256.f)-mu*mu;
  float rs=rsqrtf(var+LN_EPS);
  const float4 g4=((const float4*)gamma)[lane];
  const float4 bb4=((const float4*)beta)[lane];
  float4 y;
  y.x=gelu_exact((o.x-mu)*rs*g4.x+bb4.x);
  y.y=gelu_exact((o.y-mu)*rs*g4.y+bb4.y);
  y.z=gelu_exact((o.z-mu)*rs*g4.z+bb4.z);
  y.w=gelu_exact((o.w-mu)*rs*g4.w+bb4.w);
  if constexpr (BF16OUT){
    ushort4 p; p.x=f2bf(y.x); p.y=f2bf(y.y); p.z=f2bf(y.z); p.w=f2bf(y.w);
    ((ushort4*)((unsigned short*)gout + (size_t)d*HID))[lane] = p;
  } else {
    ((float4*)((float*)gout + (size_t)d*HID))[lane] = y;
  }
}

extern "C" void kernel_launch(void* const* d_in, const int* in_sizes, int n_in,
                              void* d_out, int out_size, void* d_ws, size_t ws_size,
                              hipStream_t stream)
{
  const float* word  = (const float*)d_in[0];
  const float* gloss = (const float*)d_in[1];
  const int*   edges = (const int*)d_in[2];
  const float* Ww=(const float*)d_in[4];  const float* bw=(const float*)d_in[5];
  const float* gw1=(const float*)d_in[6]; const float* bw1=(const float*)d_in[7];
  const float* Wc=(const float*)d_in[8];  const float* bc=(const float*)d_in[9];
  const float* gc1=(const float*)d_in[10];const float* bc1=(const float*)d_in[11];
  const float* g2_Wl=(const float*)d_in[12]; const float* g2_Wr=(const float*)d_in[13];
  const float* g2_bl=(const float*)d_in[14]; const float* g2_br=(const float*)d_in[15];
  const float* g2_att=(const float*)d_in[16];const float* g2_bias=(const float*)d_in[17];
  const float* gc2=(const float*)d_in[18];   const float* bc2=(const float*)d_in[19];
  const float* g3_Wl=(const float*)d_in[20]; const float* g3_Wr=(const float*)d_in[21];
  const float* g3_bl=(const float*)d_in[22]; const float* g3_br=(const float*)d_in[23];
  const float* g3_att=(const float*)d_in[24];const float* g3_bias=(const float*)d_in[25];
  const float* gc3=(const float*)d_in[26];   const float* bc3=(const float*)d_in[27];

  const int D  = 768;
  const int nE = in_sizes[2]/2;        // 400000
  const int nN = in_sizes[1]/D;        // 50000
  const int B  = in_sizes[0]/D;        // 512
  const int E  = nE + nN;
  const int Mpad = (nN + 127) & ~127;  // 50048
  const int chunk = (nN + 255) / 256;  // 196

  char* ws = (char*)d_ws;
  size_t o = 0;
  auto alloc = [&](size_t bytes)->char* { char* p = ws + o; o += (bytes + 255) & ~(size_t)255; return p; };
  int*   off    = (int*)  alloc((size_t)(nN+1)*4);
  int*   count  = (int*)  alloc((size_t)nN*4);      // reused as cursor after scan
  int*   bsum   = (int*)  alloc(256*4);
  int*   boff   = (int*)  alloc(256*4);
  int*   ssrc   = (int*)  alloc((size_t)E*4);
  int*   mark   = (int*)  alloc((size_t)(nN+1)*4);  // [nN] = cnt
  int*   cntp   = mark + nN;
  int*   rowmap = (int*)  alloc((size_t)nN*4);
  unsigned short* WcT = (unsigned short*)alloc((size_t)256*768*2);
  unsigned short* W2T = (unsigned short*)alloc((size_t)512*256*2);
  unsigned short* W3T = (unsigned short*)alloc((size_t)512*256*2);
  // time-shared 76.8MB buffer: glossb (cvt .. fused phase1) then Gb (gat_edge_L2 out .. dual in)
  char* uni2 = alloc((size_t)nN*D*2);
  unsigned short* glossb = (unsigned short*)uni2;
  unsigned short* Gb     = (unsigned short*)uni2;
  unsigned short* xlr = (unsigned short*)alloc((size_t)nN*512*2);   // 51.2MB
  unsigned short* xl3 = xlr;
  unsigned short* xr3 = xlr + (size_t)nN*256;

  hipMemsetAsync(count, 0, (size_t)nN*4, stream);
  hipMemsetAsync(mark, 0, (size_t)(nN+1)*4, stream);
  edge_hist_k<<<(E+255)/256, 256, 0, stream>>>(edges, count, nE, nN);
  scan1_k<<<256, 256, 0, stream>>>(count, off, bsum, nN, chunk);
  scan2_k<<<1, 256, 0, stream>>>(bsum, boff, off, nN, 256);
  scan3_k<<<256, 256, 0, stream>>>(count, boff, off, nN, chunk);
  hipMemsetAsync(count, 0, (size_t)nN*4, stream);
  edge_scatter_k<<<(E+255)/256, 256, 0, stream>>>(edges, off, count, ssrc, mark, nE, nN);
  compact_k<<<(nN+255)/256, 256, 0, stream>>>(mark, rowmap, cntp, nN);

  transpose5_k<<<192 + 4*64, 256, 0, stream>>>(Wc, WcT, g2_Wl, g2_Wr, W2T, g3_Wl, g3_Wr, W3T);

  cvt_bf16_k<<<2048, 256, 0, stream>>>(gloss, glossb, (long)nN*D);

  float* refined = (float*)d_out;                      // B*HID
  float* gnn     = (float*)d_out + (size_t)B*HID;      // LABELS*HID

  // word branch: f32 VALU (latency-tolerant small M)
  word_gemm_ln_gelu_k<<<B/4, 256, 0, stream>>>(word, Ww, bw, gw1, bw1, refined, D);

  // FUSED gloss GEMM + LN + GELU + layer-2 projections (R9 measured-best form)
  fused_gloss_proj_k<<<Mpad/BM, 512, 0, stream>>>(glossb, WcT, bc, gc1, bc1,
                                                  W2T, g2_bl, g2_br, xlr, nN);

  // GAT layer 2 edge pass -> g2 (bf16) into Gb (glossb region, now dead)
  gat_edge_k<true><<<(nN+3)/4,256,0,stream>>>(xlr,512, xlr+256,512, off,ssrc, g2_att,g2_bias,gc2,bc2, Gb, nN);

  // GAT layer 3: filtered xl (only rows needed by dst<4096 edges) + xr in one dispatch
  mfma_gemm_dual_k<<<Mpad/BM + 4096/BM, 512, 0, stream>>>(
      Gb, W3T, g3_bl, xl3, rowmap, cntp, Mpad/BM,
      W3T + 256*256, g3_br, xr3, 4096, 256);
  gat_edge_k<false><<<4096/4,256,0,stream>>>(xl3,256, xr3,256, off,ssrc, g3_att,g3_bias,gc3,bc3, gnn, 4096);
}

// Round 16
// 360.390 us; speedup vs baseline: 1.0539x; 1.0539x over previous
//
#include <hip/hip_runtime.h>
#include <hip/hip_bf16.h>

#define HID 256
#define LN_EPS 1e-5f
#define NEG_SLOPE 0.2f
#define BM 128
#define BN 256
#define BK 32

typedef __attribute__((ext_vector_type(8))) short short8;
typedef __attribute__((ext_vector_type(4))) float f32x4;

__device__ __forceinline__ float gelu_exact(float x){
  return 0.5f*x*(1.0f + erff(x*0.7071067811865476f));
}
__device__ __forceinline__ float lrelu(float x){ return x>0.f ? x : NEG_SLOPE*x; }
__device__ __forceinline__ float wave_sum64(float v){
  #pragma unroll
  for (int o=32;o>0;o>>=1) v += __shfl_xor(v,o,64);
  return v;
}
__device__ __forceinline__ void wave_sum64_x4(float& a, float& b, float& c, float& d){
  #pragma unroll
  for (int o=32;o>0;o>>=1){
    a += __shfl_xor(a,o,64);
    b += __shfl_xor(b,o,64);
    c += __shfl_xor(c,o,64);
    d += __shfl_xor(d,o,64);
  }
}
__device__ __forceinline__ unsigned short f2bf(float x){
  unsigned u = __float_as_uint(x);
  u = (u + 0x7FFFu + ((u>>16)&1u)) >> 16;
  return (unsigned short)u;
}
__device__ __forceinline__ float bf2f(unsigned short u){
  return __uint_as_float(((unsigned)u)<<16);
}
__device__ __forceinline__ void gload_lds16(const void* g, void* l){
  __builtin_amdgcn_global_load_lds((const __attribute__((address_space(1))) unsigned int*)g,
                                   (__attribute__((address_space(3))) unsigned int*)l, 16, 0, 0);
}

// ---------------- f32 -> bf16 streaming convert ----------------
__global__ __launch_bounds__(256) void cvt_bf16_k(const float* __restrict__ in,
                                                  unsigned short* __restrict__ out, long n){
  long i = ((long)blockIdx.x*blockDim.x + threadIdx.x)*8;
  const long stride = (long)gridDim.x*blockDim.x*8;
  for (; i < n; i += stride){
    float4 a = *(const float4*)(in+i);
    float4 b = *(const float4*)(in+i+4);
    short8 c;
    c[0]=(short)f2bf(a.x); c[1]=(short)f2bf(a.y); c[2]=(short)f2bf(a.z); c[3]=(short)f2bf(a.w);
    c[4]=(short)f2bf(b.x); c[5]=(short)f2bf(b.y); c[6]=(short)f2bf(b.z); c[7]=(short)f2bf(b.w);
    *(short8*)(out+i) = c;
  }
}

// ---------------- edge preprocessing: counting sort by dst ----------------
__global__ void edge_hist_k(const int* __restrict__ edges, int* __restrict__ count, int nE, int nN){
  int j = blockIdx.x*blockDim.x + threadIdx.x;
  if (j >= nE+nN) return;
  int dst = (j<nE) ? edges[nE+j] : (j-nE);
  atomicAdd(&count[dst], 1);
}

// 3-phase parallel scan
__global__ __launch_bounds__(256) void scan1_k(const int* __restrict__ count, int* __restrict__ off,
                                               int* __restrict__ bsum, int n, int chunk){
  __shared__ int sh[256];
  const int b = blockIdx.x, t = threadIdx.x;
  const int idx = b*chunk + t;
  int v = (t < chunk && idx < n) ? count[idx] : 0;
  sh[t] = v; __syncthreads();
  int val = v;
  for (int d=1; d<256; d<<=1){
    int tv = (t>=d) ? sh[t-d] : 0;
    __syncthreads();
    val += tv; sh[t] = val;
    __syncthreads();
  }
  if (t < chunk && idx < n) off[idx] = val;
  if (t == 255) bsum[b] = val;
}
__global__ __launch_bounds__(256) void scan2_k(const int* __restrict__ bsum, int* __restrict__ boff,
                                               int* __restrict__ off, int n, int nb){
  __shared__ int sh[256];
  const int t = threadIdx.x;
  int v = (t<nb) ? bsum[t] : 0;
  sh[t] = v; __syncthreads();
  int val = v;
  for (int d=1; d<256; d<<=1){
    int tv = (t>=d) ? sh[t-d] : 0;
    __syncthreads();
    val += tv; sh[t] = val;
    __syncthreads();
  }
  boff[t] = val - v;
  if (t == 255) off[n] = val;
}
__global__ __launch_bounds__(256) void scan3_k(const int* __restrict__ count, const int* __restrict__ boff,
                                               int* __restrict__ off, int n, int chunk){
  const int idx = blockIdx.x*chunk + threadIdx.x;
  if (threadIdx.x < chunk && idx < n)
    off[idx] = off[idx] - count[idx] + boff[blockIdx.x];
}

__global__ void edge_scatter_k(const int* __restrict__ edges, const int* __restrict__ off,
                               int* __restrict__ cursor, int* __restrict__ ssrc, int nE, int nN){
  int j = blockIdx.x*blockDim.x + threadIdx.x;
  if (j >= nE+nN) return;
  int src, dst;
  if (j<nE){ src=edges[j]; dst=edges[nE+j]; } else { src=j-nE; dst=src; }
  int pos = off[dst] + atomicAdd(&cursor[dst],1);
  ssrc[pos]=src;
}

// ---------------- transpose f32 (K x N) -> bf16 (N x K) ----------------
__global__ __launch_bounds__(256) void transpose_bf16_k(const float* __restrict__ in,
                                                        unsigned short* __restrict__ out, int K, int N){
  __shared__ float t[32][33];
  const int kb = blockIdx.x*32, nb = blockIdx.y*32;
  const int tx = threadIdx.x & 31, ty = threadIdx.x >> 5;
  #pragma unroll
  for (int r=ty; r<32; r+=8){
    if (kb+r < K && nb+tx < N) t[r][tx] = in[(long)(kb+r)*N + nb+tx];
  }
  __syncthreads();
  #pragma unroll
  for (int r=ty; r<32; r+=8){
    if (nb+r < N && kb+tx < K) out[(long)(nb+r)*K + kb+tx] = f2bf(t[tx][r]);
  }
}

// ---------------- word branch: VALU GEMM + bias + LN + GELU ----------------
__global__ __launch_bounds__(256) void word_gemm_ln_gelu_k(
    const float* __restrict__ X, const float* __restrict__ W,
    const float* __restrict__ bias, const float* __restrict__ gamma,
    const float* __restrict__ beta, float* __restrict__ out, int K)
{
  const int tid = threadIdx.x;
  const long row0 = (long)blockIdx.x * 4;
  float acc[4] = {0.f,0.f,0.f,0.f};
  const float* Xb = X + row0*K;
  for (int k=0;k<K;k+=4){
    float w0=W[(long)(k+0)*HID+tid];
    float w1=W[(long)(k+1)*HID+tid];
    float w2=W[(long)(k+2)*HID+tid];
    float w3=W[(long)(k+3)*HID+tid];
    #pragma unroll
    for (int r=0;r<4;r++){
      const float* xp = Xb + (long)r*K + k;
      acc[r] = fmaf(xp[0],w0, fmaf(xp[1],w1, fmaf(xp[2],w2, fmaf(xp[3],w3, acc[r]))));
    }
  }
  __shared__ float red[8];
  const float bv=bias[tid], gv=gamma[tid], btv=beta[tid];
  const int wid=tid>>6, lane=tid&63;
  #pragma unroll
  for (int r=0;r<4;r++){
    float v = acc[r]+bv;
    float p1 = wave_sum64(v), p2 = wave_sum64(v*v);
    __syncthreads();
    if (lane==0){ red[wid]=p1; red[4+wid]=p2; }
    __syncthreads();
    float S1=red[0]+red[1]+red[2]+red[3];
    float S2=red[4]+red[5]+red[6]+red[7];
    float mu = S1*(1.f/HID);
    float var = S2*(1.f/HID) - mu*mu;
    float rs = rsqrtf(var + LN_EPS);
    out[(row0+r)*HID + tid] = gelu_exact((v-mu)*rs*gv + btv);
  }
}

// ---------------- FUSED: G = gelu(LN(X@Wc+bc)); xl|xr = G@[W2l|W2r]+[bl|br] ----------------
// R9 measured-best form: phase-2 W2 staged via gload_lds 3-slot pipeline.
__global__ __launch_bounds__(512) void fused_gloss_proj_k(
    const unsigned short* __restrict__ X, const unsigned short* __restrict__ Wt,
    const float* __restrict__ bc, const float* __restrict__ gc1, const float* __restrict__ bc1,
    const unsigned short* __restrict__ W2,
    const float* __restrict__ bl, const float* __restrict__ br,
    unsigned short* __restrict__ xlr, int M)
{
  constexpr int SLOT1 = BM*BK*2 + BN*BK*2;   // 24KB
  constexpr int B2OFF = 3*SLOT1;             // 72KB (G overlays [0,64KB) after phase1)
  constexpr int SLOT2 = 256*BK*2;            // 16KB
  __shared__ __align__(16) char lds[B2OFF + 3*SLOT2];   // 120KB
  __shared__ float red_s[BM][4], red_q[BM][4];

  const int tid = threadIdx.x;
  const int wid = tid>>6, lane = tid&63;
  const int wr = wid>>2, wc = wid&3;
  const int lhi = lane>>4, llo = lane&15;
  const long r0 = (long)blockIdx.x * BM;

  // ================= phase 1: G tile =================
  {
    f32x4 acc[4][4] = {};
    long ar = r0 + (tid>>2); if (ar > (long)M-1) ar = (long)M-1;
    const unsigned short* gA  = X + ar*768 + (tid&3)*8;
    const unsigned short* gB0 = Wt + (long)(tid>>2)*768 + (tid&3)*8;
    const unsigned short* gB1 = Wt + (long)(128 + (tid>>2))*768 + (tid&3)*8;

    auto stage1 = [&](int s){
      char* b = lds + s*SLOT1;
      gload_lds16(gA,  b + tid*16);         gA  += BK;
      gload_lds16(gB0, b + 8192 + tid*16);  gB0 += BK;
      gload_lds16(gB1, b + 16384 + tid*16); gB1 += BK;
    };
    int offA[4], offB[4];
    #pragma unroll
    for (int m=0;m<4;m++) offA[m] = (wr*64 + m*16 + llo)*64 + lhi*16;
    #pragma unroll
    for (int n=0;n<4;n++) offB[n] = 8192 + (wc*64 + n*16 + llo)*64 + lhi*16;

    stage1(0); stage1(1);
    int cs = 0, ps = 2;
    for (int kt=0; kt<24; ++kt){
      if (kt+1 < 24) asm volatile("s_waitcnt vmcnt(3)" ::: "memory");
      else           asm volatile("s_waitcnt vmcnt(0)" ::: "memory");
      __builtin_amdgcn_s_barrier();
      if (kt+2 < 24) stage1(ps);
      const char* base = lds + cs*SLOT1;
      short8 a[4], b[4];
      #pragma unroll
      for (int m=0;m<4;m++) a[m] = *(const short8*)(base + offA[m]);
      #pragma unroll
      for (int n=0;n<4;n++) b[n] = *(const short8*)(base + offB[n]);
      #pragma unroll
      for (int m=0;m<4;m++)
        #pragma unroll
        for (int n=0;n<4;n++)
          acc[m][n] = __builtin_amdgcn_mfma_f32_16x16x32_bf16(a[m], b[n], acc[m][n], 0,0,0);
      cs = (cs==2)?0:cs+1;
      ps = (ps==2)?0:ps+1;
    }

    // LN + GELU epilogue -> G in LDS (chunk-XOR swizzled), overlaying staging slots
    const int colb = wc*64 + llo;
    float bv[4], gv[4], btv[4];
    #pragma unroll
    for (int n=0;n<4;n++){ bv[n]=bc[colb+n*16]; gv[n]=gc1[colb+n*16]; btv[n]=bc1[colb+n*16]; }
    __syncthreads();                      // all slot reads complete before G overwrite
    #pragma unroll
    for (int m=0;m<4;m++){
      #pragma unroll
      for (int reg=0;reg<4;reg++){
        float s=0.f, q=0.f;
        #pragma unroll
        for (int n=0;n<4;n++){ float v=acc[m][n][reg]+bv[n]; s+=v; q+=v*v; }
        #pragma unroll
        for (int msk=1;msk<16;msk<<=1){ s += __shfl_xor(s,msk,64); q += __shfl_xor(q,msk,64); }
        if (llo==0){ int rl = wr*64+m*16+lhi*4+reg; red_s[rl][wc]=s; red_q[rl][wc]=q; }
      }
    }
    __syncthreads();
    #pragma unroll
    for (int m=0;m<4;m++){
      #pragma unroll
      for (int reg=0;reg<4;reg++){
        int rl = wr*64+m*16+lhi*4+reg;
        float S1 = red_s[rl][0]+red_s[rl][1]+red_s[rl][2]+red_s[rl][3];
        float S2 = red_q[rl][0]+red_q[rl][1]+red_q[rl][2]+red_q[rl][3];
        float mu = S1*(1.f/256.f);
        float var = S2*(1.f/256.f) - mu*mu;
        float rs = rsqrtf(var + LN_EPS);
        #pragma unroll
        for (int n=0;n<4;n++){
          int col = colb + n*16;
          float y = gelu_exact((acc[m][n][reg]+bv[n]-mu)*rs*gv[n] + btv[n]);
          int byte = rl*512 + (((col>>3) ^ (rl&7))<<4) + (col&7)*2;
          *(unsigned short*)(lds + byte) = f2bf(y);
        }
      }
    }
  }
  __syncthreads();                        // G complete & visible

  // ================= phase 2: xl | xr =================
  // staging obeys gload_lds contract: dest = slot + tid*16 (wave-uniform base + lane*16)
  for (int pass=0; pass<2; ++pass){
    const unsigned short* Wp = W2 + (size_t)pass*256*256;
    const unsigned short* gW0 = Wp + (long)(tid>>2)*256 + (tid&3)*8;          // rows 0..127
    const unsigned short* gW1 = Wp + (long)(128 + (tid>>2))*256 + (tid&3)*8;  // rows 128..255
    auto stage2 = [&](int s){
      char* b = lds + B2OFF + s*SLOT2;
      gload_lds16(gW0, b + tid*16);        gW0 += BK;
      gload_lds16(gW1, b + 8192 + tid*16); gW1 += BK;
    };
    f32x4 acc2[4][4] = {};
    __syncthreads();                      // prev pass reads done before slot reuse
    stage2(0); stage2(1);
    int cs = 0, ps = 2;
    for (int kt=0; kt<8; ++kt){
      if (kt+1 < 8) asm volatile("s_waitcnt vmcnt(2)" ::: "memory");
      else          asm volatile("s_waitcnt vmcnt(0)" ::: "memory");
      __builtin_amdgcn_s_barrier();
      if (kt+2 < 8) stage2(ps);
      const char* b2base = lds + B2OFF + cs*SLOT2;
      short8 a2[4], b2[4];
      #pragma unroll
      for (int m=0;m<4;m++){
        int row = wr*64 + m*16 + llo;
        int chunk = (kt*4 + lhi) ^ (row&7);
        a2[m] = *(const short8*)(lds + row*512 + chunk*16);
      }
      #pragma unroll
      for (int n=0;n<4;n++) b2[n] = *(const short8*)(b2base + (wc*64 + n*16 + llo)*64 + lhi*16);
      #pragma unroll
      for (int m=0;m<4;m++)
        #pragma unroll
        for (int n=0;n<4;n++)
          acc2[m][n] = __builtin_amdgcn_mfma_f32_16x16x32_bf16(a2[m], b2[n], acc2[m][n], 0,0,0);
      cs = (cs==2)?0:cs+1;
      ps = (ps==2)?0:ps+1;
    }
    const int colb = wc*64 + llo;
    const float* bias = pass ? br : bl;
    float bv[4];
    #pragma unroll
    for (int n=0;n<4;n++) bv[n] = bias[colb + n*16];
    #pragma unroll
    for (int m=0;m<4;m++){
      #pragma unroll
      for (int reg=0;reg<4;reg++){
        long row = r0 + wr*64 + m*16 + lhi*4 + reg;
        if (row < M){
          #pragma unroll
          for (int n=0;n<4;n++)
            xlr[row*512 + pass*256 + colb + n*16] = f2bf(acc2[m][n][reg] + bv[n]);
        }
      }
    }
  }
}

// ---------------- MFMA GEMM, tri-buffered (MODE0, bf16 out), dual-job ----------------
__global__ __launch_bounds__(512) void mfma_gemm_dual_k(
    const unsigned short* __restrict__ X,
    const unsigned short* __restrict__ WtA, const float* __restrict__ biasA,
    unsigned short* __restrict__ outA, int MA, int nblkA,
    const unsigned short* __restrict__ WtB, const float* __restrict__ biasB,
    unsigned short* __restrict__ outB, int MB, int K)
{
  constexpr int ABYTES = BM*BK*2;
  constexpr int SLOT = ABYTES + BN*BK*2;
  __shared__ __align__(16) char lds[3*SLOT];

  const bool jobA = (int)blockIdx.x < nblkA;
  const int bx = jobA ? blockIdx.x : (blockIdx.x - nblkA);
  const unsigned short* Wt = jobA ? WtA : WtB;
  const float* bias = jobA ? biasA : biasB;
  unsigned short* out = jobA ? outA : outB;
  const int M = jobA ? MA : MB;

  const int tid = threadIdx.x;
  const int wid = tid>>6, lane = tid&63;
  const int wr = wid>>2, wc = wid&3;
  const int lhi = lane>>4, llo = lane&15;
  const long r0 = (long)bx * BM;

  f32x4 acc[4][4] = {};

  long ar = r0 + (tid>>2); if (ar > (long)M-1) ar = (long)M-1;
  const unsigned short* gA = X + ar*(long)K + (tid&3)*8;
  const unsigned short* gB0 = Wt + (long)(tid>>2)*K + (tid&3)*8;
  const unsigned short* gB1 = Wt + (long)(128 + (tid>>2))*K + (tid&3)*8;

  auto stage = [&](int s){
    char* base = lds + s*SLOT;
    gload_lds16(gA,  base + tid*16);                 gA  += BK;
    gload_lds16(gB0, base + ABYTES + tid*16);        gB0 += BK;
    gload_lds16(gB1, base + ABYTES + 8192 + tid*16); gB1 += BK;
  };

  int offA[4], offB[4];
  #pragma unroll
  for (int m=0;m<4;m++) offA[m] = (wr*64 + m*16 + llo)*64 + lhi*16;
  #pragma unroll
  for (int n=0;n<4;n++) offB[n] = ABYTES + (wc*64 + n*16 + llo)*64 + lhi*16;

  const int ksteps = K/BK;
  stage(0); stage(1);
  int cs = 0, ps = 2;
  for (int kt=0; kt<ksteps; ++kt){
    if (kt+1 < ksteps) asm volatile("s_waitcnt vmcnt(3)" ::: "memory");
    else               asm volatile("s_waitcnt vmcnt(0)" ::: "memory");
    __builtin_amdgcn_s_barrier();
    if (kt+2 < ksteps) stage(ps);
    const char* base = lds + cs*SLOT;
    short8 a[4], b[4];
    #pragma unroll
    for (int m=0;m<4;m++) a[m] = *(const short8*)(base + offA[m]);
    #pragma unroll
    for (int n=0;n<4;n++) b[n] = *(const short8*)(base + offB[n]);
    #pragma unroll
    for (int m=0;m<4;m++)
      #pragma unroll
      for (int n=0;n<4;n++)
        acc[m][n] = __builtin_amdgcn_mfma_f32_16x16x32_bf16(a[m], b[n], acc[m][n], 0,0,0);
    cs = (cs==2)?0:cs+1;
    ps = (ps==2)?0:ps+1;
  }

  const int colb = wc*64 + llo;
  float bv[4];
  #pragma unroll
  for (int n=0;n<4;n++) bv[n] = bias[colb + n*16];

  #pragma unroll
  for (int m=0;m<4;m++){
    #pragma unroll
    for (int reg=0;reg<4;reg++){
      long row = r0 + wr*64 + m*16 + lhi*4 + reg;
      if (row < M){
        #pragma unroll
        for (int n=0;n<4;n++)
          out[row*256 + colb + n*16] = f2bf(acc[m][n][reg] + bv[n]);
      }
    }
  }
}

// ---------------- per-dst GATv2 (wave per dst), 4-edge batched, online softmax + LN + GELU ----------------
template<bool BF16OUT>
__global__ __launch_bounds__(256) void gat_edge_k(
    const unsigned short* __restrict__ xl, int ldl,
    const unsigned short* __restrict__ xr, int ldr,
    const int* __restrict__ off, const int* __restrict__ ssrc,
    const float* __restrict__ att, const float* __restrict__ bias,
    const float* __restrict__ gamma, const float* __restrict__ beta,
    void* __restrict__ gout, int ndst)
{
  const int lane = threadIdx.x & 63;
  const int d = blockIdx.x*4 + (threadIdx.x>>6);
  if (d >= ndst) return;
  const float4 att4 = ((const float4*)att)[lane];
  ushort4 ru = ((const ushort4*)(xr + (size_t)d*ldr))[lane];
  const float rx=bf2f(ru.x), ry=bf2f(ru.y), rz=bf2f(ru.z), rw=bf2f(ru.w);
  const int e0=off[d], e1=off[d+1];
  float m=-1e30f, denom=0.f;
  float4 acc={0.f,0.f,0.f,0.f};

  int i = e0;
  for (; i+4 <= e1; i += 4){
    int s0=ssrc[i], s1=ssrc[i+1], s2=ssrc[i+2], s3=ssrc[i+3];
    ushort4 u0=((const ushort4*)(xl+(size_t)s0*ldl))[lane];
    ushort4 u1=((const ushort4*)(xl+(size_t)s1*ldl))[lane];
    ushort4 u2=((const ushort4*)(xl+(size_t)s2*ldl))[lane];
    ushort4 u3=((const ushort4*)(xl+(size_t)s3*ldl))[lane];
    float a0x=bf2f(u0.x),a0y=bf2f(u0.y),a0z=bf2f(u0.z),a0w=bf2f(u0.w);
    float a1x=bf2f(u1.x),a1y=bf2f(u1.y),a1z=bf2f(u1.z),a1w=bf2f(u1.w);
    float a2x=bf2f(u2.x),a2y=bf2f(u2.y),a2z=bf2f(u2.z),a2w=bf2f(u2.w);
    float a3x=bf2f(u3.x),a3y=bf2f(u3.y),a3z=bf2f(u3.z),a3w=bf2f(u3.w);
    float e0v = att4.x*lrelu(a0x+rx)+att4.y*lrelu(a0y+ry)+att4.z*lrelu(a0z+rz)+att4.w*lrelu(a0w+rw);
    float e1v = att4.x*lrelu(a1x+rx)+att4.y*lrelu(a1y+ry)+att4.z*lrelu(a1z+rz)+att4.w*lrelu(a1w+rw);
    float e2v = att4.x*lrelu(a2x+rx)+att4.y*lrelu(a2y+ry)+att4.z*lrelu(a2z+rz)+att4.w*lrelu(a2w+rw);
    float e3v = att4.x*lrelu(a3x+rx)+att4.y*lrelu(a3y+ry)+att4.z*lrelu(a3z+rz)+att4.w*lrelu(a3w+rw);
    wave_sum64_x4(e0v, e1v, e2v, e3v);
    float bm = fmaxf(fmaxf(e0v,e1v), fmaxf(e2v,e3v));
    if (bm > m){
      float sc = expf(m - bm);
      denom *= sc; acc.x*=sc; acc.y*=sc; acc.z*=sc; acc.w*=sc;
      m = bm;
    }
    float x0=expf(e0v-m), x1=expf(e1v-m), x2=expf(e2v-m), x3=expf(e3v-m);
    denom += x0+x1+x2+x3;
    acc.x += x0*a0x + x1*a1x + x2*a2x + x3*a3x;
    acc.y += x0*a0y + x1*a1y + x2*a2y + x3*a3y;
    acc.z += x0*a0z + x1*a1z + x2*a2z + x3*a3z;
    acc.w += x0*a0w + x1*a1w + x2*a2w + x3*a3w;
  }
  for (; i < e1; ++i){
    int src=ssrc[i];
    ushort4 au = ((const ushort4*)(xl + (size_t)src*ldl))[lane];
    float ax=bf2f(au.x), ay=bf2f(au.y), az=bf2f(au.z), aw=bf2f(au.w);
    float e = att4.x*lrelu(ax+rx)+att4.y*lrelu(ay+ry)
            + att4.z*lrelu(az+rz)+att4.w*lrelu(aw+rw);
    e = wave_sum64(e);
    if (e > m){
      float sc = expf(m - e);
      denom *= sc; acc.x*=sc; acc.y*=sc; acc.z*=sc; acc.w*=sc;
      m = e;
    }
    float ee = expf(e - m);
    denom += ee;
    acc.x += ee*ax; acc.y += ee*ay; acc.z += ee*az; acc.w += ee*aw;
  }

  float inv = 1.0f/denom;
  const float4 b4=((const float4*)bias)[lane];
  float4 o;
  o.x=acc.x*inv+b4.x; o.y=acc.y*inv+b4.y; o.z=acc.z*inv+b4.z; o.w=acc.w*inv+b4.w;
  float S1 = wave_sum64(o.x+o.y+o.z+o.w);
  float S2 = wave_sum64(o.x*o.x+o.y*o.y+o.z*o.z+o.w*o.w);
  float mu=S1*(1.f/256.f);
  float var=S2*(1.f/256.f)-mu*mu;
  float rs=rsqrtf(var+LN_EPS);
  const float4 g4=((const float4*)gamma)[lane];
  const float4 bb4=((const float4*)beta)[lane];
  float4 y;
  y.x=gelu_exact((o.x-mu)*rs*g4.x+bb4.x);
  y.y=gelu_exact((o.y-mu)*rs*g4.y+bb4.y);
  y.z=gelu_exact((o.z-mu)*rs*g4.z+bb4.z);
  y.w=gelu_exact((o.w-mu)*rs*g4.w+bb4.w);
  if constexpr (BF16OUT){
    ushort4 p; p.x=f2bf(y.x); p.y=f2bf(y.y); p.z=f2bf(y.z); p.w=f2bf(y.w);
    ((ushort4*)((unsigned short*)gout + (size_t)d*HID))[lane] = p;
  } else {
    ((float4*)((float*)gout + (size_t)d*HID))[lane] = y;
  }
}

extern "C" void kernel_launch(void* const* d_in, const int* in_sizes, int n_in,
                              void* d_out, int out_size, void* d_ws, size_t ws_size,
                              hipStream_t stream)
{
  const float* word  = (const float*)d_in[0];
  const float* gloss = (const float*)d_in[1];
  const int*   edges = (const int*)d_in[2];
  const float* Ww=(const float*)d_in[4];  const float* bw=(const float*)d_in[5];
  const float* gw1=(const float*)d_in[6]; const float* bw1=(const float*)d_in[7];
  const float* Wc=(const float*)d_in[8];  const float* bc=(const float*)d_in[9];
  const float* gc1=(const float*)d_in[10];const float* bc1=(const float*)d_in[11];
  const float* g2_Wl=(const float*)d_in[12]; const float* g2_Wr=(const float*)d_in[13];
  const float* g2_bl=(const float*)d_in[14]; const float* g2_br=(const float*)d_in[15];
  const float* g2_att=(const float*)d_in[16];const float* g2_bias=(const float*)d_in[17];
  const float* gc2=(const float*)d_in[18];   const float* bc2=(const float*)d_in[19];
  const float* g3_Wl=(const float*)d_in[20]; const float* g3_Wr=(const float*)d_in[21];
  const float* g3_bl=(const float*)d_in[22]; const float* g3_br=(const float*)d_in[23];
  const float* g3_att=(const float*)d_in[24];const float* g3_bias=(const float*)d_in[25];
  const float* gc3=(const float*)d_in[26];   const float* bc3=(const float*)d_in[27];

  const int D  = 768;
  const int nE = in_sizes[2]/2;        // 400000
  const int nN = in_sizes[1]/D;        // 50000
  const int B  = in_sizes[0]/D;        // 512
  const int E  = nE + nN;
  const int Mpad = (nN + 127) & ~127;  // 50048
  const int chunk = (nN + 255) / 256;  // 196

  char* ws = (char*)d_ws;
  size_t o = 0;
  auto alloc = [&](size_t bytes)->char* { char* p = ws + o; o += (bytes + 255) & ~(size_t)255; return p; };
  int*   off    = (int*)  alloc((size_t)(nN+1)*4);
  int*   count  = (int*)  alloc((size_t)nN*4);      // reused as cursor after scan
  int*   bsum   = (int*)  alloc(256*4);
  int*   boff   = (int*)  alloc(256*4);
  int*   ssrc   = (int*)  alloc((size_t)E*4);
  unsigned short* WcT = (unsigned short*)alloc((size_t)256*768*2);
  unsigned short* W2T = (unsigned short*)alloc((size_t)512*256*2);
  unsigned short* W3T = (unsigned short*)alloc((size_t)512*256*2);
  // time-shared 76.8MB buffer: glossb (cvt .. fused phase1) then Gb (gat_edge_L2 out .. dual in)
  char* uni2 = alloc((size_t)nN*D*2);
  unsigned short* glossb = (unsigned short*)uni2;
  unsigned short* Gb     = (unsigned short*)uni2;
  unsigned short* xlr = (unsigned short*)alloc((size_t)nN*512*2);   // 51.2MB
  unsigned short* xl3 = xlr;
  unsigned short* xr3 = xlr + (size_t)nN*256;

  hipMemsetAsync(count, 0, (size_t)nN*4, stream);
  edge_hist_k<<<(E+255)/256, 256, 0, stream>>>(edges, count, nE, nN);
  scan1_k<<<256, 256, 0, stream>>>(count, off, bsum, nN, chunk);
  scan2_k<<<1, 256, 0, stream>>>(bsum, boff, off, nN, 256);
  scan3_k<<<256, 256, 0, stream>>>(count, boff, off, nN, chunk);
  hipMemsetAsync(count, 0, (size_t)nN*4, stream);
  edge_scatter_k<<<(E+255)/256, 256, 0, stream>>>(edges, off, count, ssrc, nE, nN);

  transpose_bf16_k<<<dim3(24,8),256,0,stream>>>(Wc, WcT, 768,256);
  transpose_bf16_k<<<dim3(8,8),256,0,stream>>>(g2_Wl, W2T, 256,256);
  transpose_bf16_k<<<dim3(8,8),256,0,stream>>>(g2_Wr, W2T + 256*256, 256,256);
  transpose_bf16_k<<<dim3(8,8),256,0,stream>>>(g3_Wl, W3T, 256,256);
  transpose_bf16_k<<<dim3(8,8),256,0,stream>>>(g3_Wr, W3T + 256*256, 256,256);

  cvt_bf16_k<<<2048, 256, 0, stream>>>(gloss, glossb, (long)nN*D);

  float* refined = (float*)d_out;                      // B*HID
  float* gnn     = (float*)d_out + (size_t)B*HID;      // LABELS*HID

  // word branch: f32 VALU (latency-tolerant small M)
  word_gemm_ln_gelu_k<<<B/4, 256, 0, stream>>>(word, Ww, bw, gw1, bw1, refined, D);

  // FUSED gloss GEMM + LN + GELU + layer-2 projections
  fused_gloss_proj_k<<<Mpad/BM, 512, 0, stream>>>(glossb, WcT, bc, gc1, bc1,
                                                  W2T, g2_bl, g2_br, xlr, nN);

  // GAT layer 2 edge pass -> g2 (bf16) into Gb (glossb region, now dead)
  gat_edge_k<true><<<(nN+3)/4,256,0,stream>>>(xlr,512, xlr+256,512, off,ssrc, g2_att,g2_bias,gc2,bc2, Gb, nN);

  // GAT layer 3: xl (391 blocks) + xr (32 blocks) fused into one dispatch
  mfma_gemm_dual_k<<<Mpad/BM + 4096/BM, 512, 0, stream>>>(
      Gb, W3T, g3_bl, xl3, nN, Mpad/BM,
      W3T + 256*256, g3_br, xr3, 4096, 256);
  gat_edge_k<false><<<4096/4,256,0,stream>>>(xl3,256, xr3,256, off,ssrc, g3_att,g3_bias,gc3,bc3, gnn, 4096);
}